// Round 1
// baseline (33.524 us; speedup 1.0000x reference)
//
#include <hip/hip_runtime.h>

// Problem constants (from reference): E=8, B=4, S=4096, H=1024, K=2
static constexpr int kB = 4;
static constexpr int kS = 4096;
static constexpr int kH = 1024;
static constexpr int kK = 2;
static constexpr int kTokens = kB * kS;                  // 16384
static constexpr size_t kBSH = (size_t)kB * kS * kH;     // 16,777,216

// One block per token; 256 threads x float4 = 1024 floats = one H-row.
__global__ __launch_bounds__(256) void FusedExpertMixer_kernel(
    const float* __restrict__ expert_stack,   // [E,B,S,H]
    const float* __restrict__ expert_weights, // [B,S,K]
    const int*   __restrict__ expert_indices, // [B,S,K]
    float* __restrict__ out)                  // [B,S,H]
{
    const int t = blockIdx.x;                 // token index in [0, B*S)

    // Scalar (wave-uniform) loads of the two indices/weights for this token.
    const int   e0 = expert_indices[t * kK + 0];
    const int   e1 = expert_indices[t * kK + 1];
    const float w0 = expert_weights[t * kK + 0];
    const float w1 = expert_weights[t * kK + 1];

    const float4* __restrict__ a =
        (const float4*)(expert_stack + (size_t)e0 * kBSH + (size_t)t * kH);
    const float4* __restrict__ b =
        (const float4*)(expert_stack + (size_t)e1 * kBSH + (size_t)t * kH);
    float4* __restrict__ o = (float4*)(out + (size_t)t * kH);

    const int h = threadIdx.x;                // 0..255, one float4 each
    const float4 va = a[h];
    const float4 vb = b[h];
    float4 r;
    r.x = w0 * va.x + w1 * vb.x;
    r.y = w0 * va.y + w1 * vb.y;
    r.z = w0 * va.z + w1 * vb.z;
    r.w = w0 * va.w + w1 * vb.w;
    o[h] = r;
}

extern "C" void kernel_launch(void* const* d_in, const int* in_sizes, int n_in,
                              void* d_out, int out_size, void* d_ws, size_t ws_size,
                              hipStream_t stream) {
    // Input order per setup_inputs(): hidden_states, expert_stack,
    // expert_weights, expert_indices. hidden_states is unused by the
    // reference computation.
    const float* expert_stack   = (const float*)d_in[1];
    const float* expert_weights = (const float*)d_in[2];
    const int*   expert_indices = (const int*)d_in[3];
    float* out = (float*)d_out;

    dim3 grid(kTokens);
    dim3 block(256);
    FusedExpertMixer_kernel<<<grid, block, 0, stream>>>(
        expert_stack, expert_weights, expert_indices, out);
}